// Round 11
// baseline (193.284 us; speedup 1.0000x reference)
//
#include <hip/hip_runtime.h>

typedef __attribute__((ext_vector_type(8))) short short8;
typedef __attribute__((ext_vector_type(4))) float f32x4;

static __device__ __forceinline__ unsigned short f2bf(float f) {
  return (unsigned short)((__builtin_bit_cast(unsigned int, f) + 0x8000u) >> 16);
}
static __device__ __forceinline__ unsigned cvtpk(float a, float b) {
  unsigned r;
  asm("v_cvt_pk_bf16_f32 %0, %1, %2" : "=v"(r) : "v"(a), "v"(b));
  return r;
}

// B=1, Z=H=W=64, C=96, NH=3, HD=32, WS=4, SS=2, N=64 tok/window, NW=4096
constexpr float LOG2E = 1.4426950408889634f;
constexpr float QSCL = 0.17677669529663687f * LOG2E;  // SCL * log2(e), folded into Q
constexpr int XP = 104;   // 208B = 52 dw ≡ 20 (mod 32)
constexpr int KP = 104;
constexpr int VTP = 72;   // 144B

// source index into W[outC][K] for frag-linear element o:
// o = (f*64 + lane)*8 + j ; f = tile*(K/32) + ks
static __device__ __forceinline__ int frag_src(int o, int K) {
  const int j = o & 7;
  const int lane = (o >> 3) & 63;
  const int f = o >> 9;
  const int nks = K >> 5;
  const int ks = f % nks;
  const int t = f / nks;
  const int row = t * 16 + (lane & 15);
  const int k = ks * 32 + (lane >> 4) * 8 + j;
  return row * K + k;
}

// ---- prep: weights -> bf16 frag-linear; (bias+mask)*log2e -> fp32 table ----
// table layout: [v][h][nt][q][kg][r]
__global__ void prep_kernel(const float* __restrict__ qkvw, const float* __restrict__ projw,
                            const float* __restrict__ fc1w, const float* __restrict__ fc2w,
                            const float* __restrict__ relbias,
                            unsigned short* __restrict__ ws, float* __restrict__ tab) {
  int i = blockIdx.x * 256 + threadIdx.x;
  if (i < 27648) ws[i] = f2bf(qkvw[frag_src(i, 96)]);
  if (i < 9216)  ws[27648 + i] = f2bf(projw[frag_src(i, 96)]);
  if (i < 36864) {
    ws[36864 + i] = f2bf(fc1w[frag_src(i, 96)]);
    ws[73728 + i] = f2bf(fc2w[frag_src(i, 384)]);
  }
  if (i < 98304) {
    const int r = i & 3, kgi = (i >> 2) & 3, q = (i >> 4) & 63, nt = (i >> 10) & 3;
    const int vh = i >> 12;           // v*3 + h
    const int h = vh % 3, v = vh / 3;
    const int key = nt * 16 + kgi * 4 + r;
    const bool bz = v & 4, bh = v & 2, bw = v & 1;
    const int iz = q >> 4, ih = (q >> 2) & 3, iw = q & 3;
    const int jz = key >> 4, jh = (key >> 2) & 3, jw = key & 3;
    const int idx = (iz - jz + 3) * 49 + (ih - jh + 3) * 7 + (iw - jw + 3);
    const int ci = (bz ? (iz < 2 ? 9 : 18) : 0) + (bh ? (ih < 2 ? 3 : 6) : 0) +
                   (bw ? (iw < 2 ? 1 : 2) : 0);
    const int cj = (bz ? (jz < 2 ? 9 : 18) : 0) + (bh ? (jh < 2 ? 3 : 6) : 0) +
                   (bw ? (jw < 2 ? 1 : 2) : 0);
    tab[i] = (relbias[idx * 3 + h] + (ci != cj ? -100.f : 0.f)) * LOG2E;
  }
}

// --------- fully fused: LN1+shift+MSA+proj+res + LN2+FC1+GELU+FC2+res -------
__global__ __launch_bounds__(256, 4) void fused_kernel(
    const float* __restrict__ x,
    const float* __restrict__ n1w, const float* __restrict__ n1b,
    const float* __restrict__ qkvb, const float* __restrict__ tab,
    const float* __restrict__ projb,
    const float* __restrict__ n2w, const float* __restrict__ n2b,
    const float* __restrict__ b1, const float* __restrict__ b2,
    const unsigned short* __restrict__ wq, const unsigned short* __restrict__ wp,
    const unsigned short* __restrict__ w1, const unsigned short* __restrict__ w2,
    float* __restrict__ out) {
  __shared__ unsigned short Xo[64 * XP];   // X_ln -> O -> xln2
  __shared__ unsigned short Kb[64 * KP];   // Q -> K overlay -> H1 chunk
  __shared__ unsigned short Vt[96 * VTP];  // [h*32+d][token]

  const int tid = threadIdx.x;
  const int bid = blockIdx.x;
  const int wz = bid >> 8, wh = (bid >> 4) & 15, ww = bid & 15;
  const int wave = tid >> 6, lane = tid & 63;
  const int ln = lane & 15, kg = lane >> 4;

  // Phase 0: gather (cyclic shift) + LayerNorm1 -> Xo (wave-local rows)
  {
    const int n = tid >> 2, part = tid & 3;
    const int lz = n >> 4, lh = (n >> 2) & 3, lw = n & 3;
    const int sz = (wz * 4 + lz + 2) & 63;
    const int sh = (wh * 4 + lh + 2) & 63;
    const int sw = (ww * 4 + lw + 2) & 63;
    const float* px = x + (size_t)((sz * 64 + sh) * 64 + sw) * 96 + part * 24;
    float4 v[6];
#pragma unroll
    for (int j = 0; j < 6; ++j) v[j] = ((const float4*)px)[j];
    float s = 0.f, sq = 0.f;
#pragma unroll
    for (int j = 0; j < 6; ++j) {
      s += v[j].x + v[j].y + v[j].z + v[j].w;
      sq += v[j].x * v[j].x + v[j].y * v[j].y + v[j].z * v[j].z + v[j].w * v[j].w;
    }
    s += __shfl_xor(s, 1);  s += __shfl_xor(s, 2);
    sq += __shfl_xor(sq, 1); sq += __shfl_xor(sq, 2);
    const float mean = s * (1.f / 96.f);
    const float var = sq * (1.f / 96.f) - mean * mean;
    const float rs = rsqrtf(var + 1e-5f);
    const float4* g4 = (const float4*)(n1w + part * 24);
    const float4* b4 = (const float4*)(n1b + part * 24);
#pragma unroll
    for (int j = 0; j < 6; ++j) {
      float4 g = g4[j], b = b4[j];
      uint2 o;
      o.x = cvtpk((v[j].x - mean) * rs * g.x + b.x, (v[j].y - mean) * rs * g.y + b.y);
      o.y = cvtpk((v[j].z - mean) * rs * g.z + b.z, (v[j].w - mean) * rs * g.w + b.w);
      *(uint2*)&Xo[n * XP + part * 24 + j * 4] = o;
    }
  }
  // no barrier: phase 1 reads only own-wave Xo rows

  // Phase 1: QKV GEMM, 6-frag register batches. Q pre-scaled by SCL*log2e.
  short8 qa[3];
  {
    short8 a[3];
#pragma unroll
    for (int ks = 0; ks < 3; ++ks)
      a[ks] = *(const short8*)&Xo[(wave * 16 + ln) * XP + ks * 32 + kg * 8];
    // ---- Q (frags 0..17, three 6-batches) ----
#pragma unroll
    for (int g = 0; g < 3; ++g) {
      short8 wf[6];
#pragma unroll
      for (int f = 0; f < 6; ++f)
        wf[f] = *(const short8*)&wq[(size_t)(g * 6 + f) * 512 + lane * 8];
#pragma unroll
      for (int t = 0; t < 2; ++t) {
        const int nt = g * 2 + t;
        const int oc = nt * 16 + ln;
        f32x4 acc = {0.f, 0.f, 0.f, 0.f};
#pragma unroll
        for (int ks = 0; ks < 3; ++ks)
          acc = __builtin_amdgcn_mfma_f32_16x16x32_bf16(a[ks], wf[t * 3 + ks], acc, 0, 0, 0);
        const float bias = qkvb[oc];
#pragma unroll
        for (int r = 0; r < 4; ++r)
          Kb[(wave * 16 + kg * 4 + r) * KP + oc] = f2bf((acc[r] + bias) * QSCL);
      }
    }
    // qa frags (own-wave rows; same-wave in-order LDS allows K overlay after)
#pragma unroll
    for (int h = 0; h < 3; ++h)
      qa[h] = *(const short8*)&Kb[(wave * 16 + ln) * KP + h * 32 + kg * 8];
    // ---- K (frags 18..35), overlays Q region ----
#pragma unroll
    for (int g = 0; g < 3; ++g) {
      short8 wf[6];
#pragma unroll
      for (int f = 0; f < 6; ++f)
        wf[f] = *(const short8*)&wq[(size_t)(18 + g * 6 + f) * 512 + lane * 8];
#pragma unroll
      for (int t = 0; t < 2; ++t) {
        const int nt = g * 2 + t;
        const int oc = 96 + nt * 16 + ln;
        f32x4 acc = {0.f, 0.f, 0.f, 0.f};
#pragma unroll
        for (int ks = 0; ks < 3; ++ks)
          acc = __builtin_amdgcn_mfma_f32_16x16x32_bf16(a[ks], wf[t * 3 + ks], acc, 0, 0, 0);
        const float bias = qkvb[oc];
#pragma unroll
        for (int r = 0; r < 4; ++r)
          Kb[(wave * 16 + kg * 4 + r) * KP + nt * 16 + ln] = f2bf(acc[r] + bias);
      }
    }
    // ---- V (frags 36..53) -> Vt transposed ----
#pragma unroll
    for (int g = 0; g < 3; ++g) {
      short8 wf[6];
#pragma unroll
      for (int f = 0; f < 6; ++f)
        wf[f] = *(const short8*)&wq[(size_t)(36 + g * 6 + f) * 512 + lane * 8];
#pragma unroll
      for (int t = 0; t < 2; ++t) {
        const int nt = g * 2 + t;
        const int oc = 192 + nt * 16 + ln;
        f32x4 acc = {0.f, 0.f, 0.f, 0.f};
#pragma unroll
        for (int ks = 0; ks < 3; ++ks)
          acc = __builtin_amdgcn_mfma_f32_16x16x32_bf16(a[ks], wf[t * 3 + ks], acc, 0, 0, 0);
        const float bias = qkvb[oc];
        uint2 u;
        u.x = cvtpk(acc[0] + bias, acc[1] + bias);
        u.y = cvtpk(acc[2] + bias, acc[3] + bias);
        *(uint2*)&Vt[(nt * 16 + ln) * VTP + wave * 16 + kg * 4] = u;
      }
    }
  }
  __syncthreads();  // K, Vt read cross-wave in phase 2

  // Phase 2: transposed QK^T (S^T = K·Q^T) -> in-register softmax (exp2) -> PV
  const int vv = ((wz == 15) ? 4 : 0) | ((wh == 15) ? 2 : 0) | ((ww == 15) ? 1 : 0);
  const float* tb0 = tab + (size_t)(vv * 3) * 4096;
  const int rowbase = wave * 16 + kg * 4;
  const int lA = ((kg & 1) << 5) + ln;   // source lane kg' = 2*(kg&1)
  const int lB = lA + 16;                // source lane kg' = 2*(kg&1)+1
#pragma unroll
  for (int h = 0; h < 3; ++h) {
    const float* tb = tb0 + h * 4096;
    f32x4 e[4];
#pragma unroll
    for (int nt = 0; nt < 4; ++nt) {
      short8 kf = *(const short8*)&Kb[(nt * 16 + ln) * KP + h * 32 + kg * 8];
      f32x4 trow = *(const f32x4*)(tb + nt * 1024 + (wave * 16 + ln) * 16 + kg * 4);
      f32x4 z = {0.f, 0.f, 0.f, 0.f};
      f32x4 st = __builtin_amdgcn_mfma_f32_16x16x32_bf16(kf, qa[h], z, 0, 0, 0);
#pragma unroll
      for (int r = 0; r < 4; ++r)
        e[nt][r] = __builtin_amdgcn_exp2f(st[r] + trow[r]);  // bounded: no max-sub
    }
    float hs = 0.f;
#pragma unroll
    for (int nt = 0; nt < 4; ++nt)
#pragma unroll
      for (int r = 0; r < 4; ++r) hs += e[nt][r];
    hs += __shfl_xor(hs, 16);
    hs += __shfl_xor(hs, 32);
    const float inv = __builtin_amdgcn_rcpf(hs);
    unsigned pp[4][2];
#pragma unroll
    for (int nt = 0; nt < 4; ++nt) {
      pp[nt][0] = cvtpk(e[nt][0] * inv, e[nt][1] * inv);
      pp[nt][1] = cvtpk(e[nt][2] * inv, e[nt][3] * inv);
    }
    // exchange -> PV A-frags
    short8 paf[2];
#pragma unroll
    for (int ks = 0; ks < 2; ++ks) {
      const unsigned a0 = __shfl((int)pp[2 * ks][0], lA);
      const unsigned a1 = __shfl((int)pp[2 * ks][1], lA);
      const unsigned a2 = __shfl((int)pp[2 * ks][0], lB);
      const unsigned a3 = __shfl((int)pp[2 * ks][1], lB);
      const unsigned b0 = __shfl((int)pp[2 * ks + 1][0], lA);
      const unsigned b1 = __shfl((int)pp[2 * ks + 1][1], lA);
      const unsigned b2 = __shfl((int)pp[2 * ks + 1][0], lB);
      const unsigned b3 = __shfl((int)pp[2 * ks + 1][1], lB);
      const bool hi = (kg >> 1) != 0;
      uint4 wv;
      wv.x = hi ? b0 : a0;
      wv.y = hi ? b1 : a1;
      wv.z = hi ? b2 : a2;
      wv.w = hi ? b3 : a3;
      paf[ks] = __builtin_bit_cast(short8, wv);
    }
#pragma unroll
    for (int dt = 0; dt < 2; ++dt) {
      f32x4 oacc = {0.f, 0.f, 0.f, 0.f};
#pragma unroll
      for (int ks = 0; ks < 2; ++ks) {
        short8 vb = *(const short8*)&Vt[(h * 32 + dt * 16 + ln) * VTP + ks * 32 + kg * 8];
        oacc = __builtin_amdgcn_mfma_f32_16x16x32_bf16(paf[ks], vb, oacc, 0, 0, 0);
      }
#pragma unroll
      for (int r = 0; r < 4; ++r)
        Xo[(rowbase + r) * XP + h * 32 + dt * 16 + ln] = f2bf(oacc[r]);
    }
  }
  // no barrier: phase 3 reads only own-wave Xo rows

  // Phase 3 pass A: proj + shortcut -> write raw x2 to out; accumulate LN2 stats
  int gtok[4];
  float mean_[4], rs_[4];
  {
#pragma unroll
    for (int r = 0; r < 4; ++r) {
      const int n = rowbase + r;
      const int lz = n >> 4, lh = (n >> 2) & 3, lw = n & 3;
      const int oz = (wz * 4 + lz + 2) & 63;
      const int oh = (wh * 4 + lh + 2) & 63;
      const int ow = (ww * 4 + lw + 2) & 63;
      gtok[r] = (oz * 64 + oh) * 64 + ow;
    }
    short8 oa[3];
#pragma unroll
    for (int ks = 0; ks < 3; ++ks)
      oa[ks] = *(const short8*)&Xo[(wave * 16 + ln) * XP + ks * 32 + kg * 8];
    float s_[4] = {0.f, 0.f, 0.f, 0.f}, sq_[4] = {0.f, 0.f, 0.f, 0.f};
#pragma unroll
    for (int g = 0; g < 3; ++g) {
      short8 wf[6];
#pragma unroll
      for (int f = 0; f < 6; ++f)
        wf[f] = *(const short8*)&wp[(size_t)(g * 6 + f) * 512 + lane * 8];
#pragma unroll
      for (int t = 0; t < 2; ++t) {
        const int nt = g * 2 + t;
        const int col = nt * 16 + ln;
        f32x4 acc = {0.f, 0.f, 0.f, 0.f};
#pragma unroll
        for (int ks = 0; ks < 3; ++ks)
          acc = __builtin_amdgcn_mfma_f32_16x16x32_bf16(oa[ks], wf[t * 3 + ks], acc, 0, 0, 0);
        const float pbv = projb[col];
#pragma unroll
        for (int r = 0; r < 4; ++r) {
          const float v = x[(size_t)gtok[r] * 96 + col] + acc[r] + pbv;
          s_[r] += v;
          sq_[r] += v * v;
          out[(size_t)gtok[r] * 96 + col] = v;   // raw x2 (re-read below; RMW in epilogue)
        }
      }
    }
#pragma unroll
    for (int r = 0; r < 4; ++r) {
      float s = s_[r], sq = sq_[r];
      s += __shfl_xor(s, 1);  s += __shfl_xor(s, 2);
      s += __shfl_xor(s, 4);  s += __shfl_xor(s, 8);
      sq += __shfl_xor(sq, 1); sq += __shfl_xor(sq, 2);
      sq += __shfl_xor(sq, 4); sq += __shfl_xor(sq, 8);
      const float mean = s * (1.f / 96.f);
      const float var = sq * (1.f / 96.f) - mean * mean;
      mean_[r] = mean;
      rs_[r] = rsqrtf(var + 1e-5f);
    }
  }
  // Phase 3 pass B: reload x2 (L2-hot, same thread) -> LN2 -> xln2 into Xo
#pragma unroll
  for (int nt = 0; nt < 6; ++nt) {
    const int col = nt * 16 + ln;
    const float gw = n2w[col], gb = n2b[col];
#pragma unroll
    for (int r = 0; r < 4; ++r) {
      const float v = out[(size_t)gtok[r] * 96 + col];
      const float xl = (v - mean_[r]) * rs_[r] * gw + gb;
      Xo[(rowbase + r) * XP + col] = f2bf(xl);
    }
  }

  // xln2 A-frags (own-wave rows)
  short8 a2[3];
#pragma unroll
  for (int ks = 0; ks < 3; ++ks)
    a2[ks] = *(const short8*)&Xo[(wave * 16 + ln) * XP + ks * 32 + kg * 8];

  __syncthreads();  // all waves done reading K (phase 2) before H1 overlays Kb

  // Phase 4: MLP — FC1 (3-frag batches) + poly-GELU -> Kb, FC2 (3-frag groups)
  f32x4 facc[6];
#pragma unroll
  for (int nt = 0; nt < 6; ++nt) facc[nt] = (f32x4){0.f, 0.f, 0.f, 0.f};
#pragma unroll 1
  for (int c = 0; c < 4; ++c) {
#pragma unroll
    for (int nt2 = 0; nt2 < 6; ++nt2) {
      short8 wf1[3];
#pragma unroll
      for (int ks = 0; ks < 3; ++ks)
        wf1[ks] = *(const short8*)&w1[(size_t)(c * 18 + nt2 * 3 + ks) * 512 + lane * 8];
      f32x4 acc = {0.f, 0.f, 0.f, 0.f};
#pragma unroll
      for (int ks = 0; ks < 3; ++ks)
        acc = __builtin_amdgcn_mfma_f32_16x16x32_bf16(a2[ks], wf1[ks], acc, 0, 0, 0);
      const float bb = b1[c * 96 + nt2 * 16 + ln];
#pragma unroll
      for (int r = 0; r < 4; ++r) {
        const float v = acc[r] + bb;
        // gelu via odd-poly CDF approx + clamp (no trans ops)
        const float t2 = v * v;
        float p = fmaf(0.004287f, t2, -0.05694f);
        p = fmaf(p, t2, 0.3952f);
        float phi = fmaf(p, v, 0.5f);
        phi = fminf(fmaxf(phi, 0.f), 1.f);
        Kb[(rowbase + r) * KP + nt2 * 16 + ln] = f2bf(v * phi);
      }
    }
#pragma unroll
    for (int ks2 = 0; ks2 < 3; ++ks2) {
      short8 pa = *(const short8*)&Kb[(wave * 16 + ln) * KP + ks2 * 32 + kg * 8];
#pragma unroll
      for (int g2 = 0; g2 < 2; ++g2) {
        short8 wf2[3];
#pragma unroll
        for (int t = 0; t < 3; ++t)
          wf2[t] = *(const short8*)&w2[(size_t)((g2 * 3 + t) * 12 + c * 3 + ks2) * 512 + lane * 8];
#pragma unroll
        for (int t = 0; t < 3; ++t)
          facc[g2 * 3 + t] =
              __builtin_amdgcn_mfma_f32_16x16x32_bf16(pa, wf2[t], facc[g2 * 3 + t], 0, 0, 0);
      }
    }
  }
  // Epilogue: out += fc2 + b2 (RMW; x2 already there)
#pragma unroll
  for (int nt = 0; nt < 6; ++nt) {
    const int col = nt * 16 + ln;
    const float bb = b2[col];
#pragma unroll
    for (int r = 0; r < 4; ++r) {
      const size_t idx = (size_t)gtok[r] * 96 + col;
      out[idx] = out[idx] + facc[nt][r] + bb;
    }
  }
}

extern "C" void kernel_launch(void* const* d_in, const int* in_sizes, int n_in,
                              void* d_out, int out_size, void* d_ws, size_t ws_size,
                              hipStream_t stream) {
  const float* x    = (const float*)d_in[0];
  const float* n1w  = (const float*)d_in[1];
  const float* n1b  = (const float*)d_in[2];
  const float* qkvw = (const float*)d_in[3];
  const float* qkvb = (const float*)d_in[4];
  const float* relb = (const float*)d_in[5];
  const float* pw   = (const float*)d_in[6];
  const float* pb   = (const float*)d_in[7];
  const float* n2w  = (const float*)d_in[8];
  const float* n2b  = (const float*)d_in[9];
  const float* w1   = (const float*)d_in[10];
  const float* b1   = (const float*)d_in[11];
  const float* w2   = (const float*)d_in[12];
  const float* b2   = (const float*)d_in[13];
  float* out = (float*)d_out;

  unsigned short* wsq = (unsigned short*)d_ws;   // 27648 bf16 frag-linear
  unsigned short* wsp = wsq + 27648;             // 9216
  unsigned short* ws1 = wsp + 9216;              // 36864
  unsigned short* ws2 = ws1 + 36864;             // 36864
  float* tab = (float*)(wsq + 110592);           // 98304 fp32 bias+mask table

  hipLaunchKernelGGL(prep_kernel, dim3(384), dim3(256), 0, stream,
                     qkvw, pw, w1, w2, relb, wsq, tab);
  hipLaunchKernelGGL(fused_kernel, dim3(4096), dim3(256), 0, stream,
                     x, n1w, n1b, qkvb, tab, pb, n2w, n2b, b1, b2,
                     wsq, wsp, ws1, ws2, out);
}

// Round 12
// 160.080 us; speedup vs baseline: 1.2074x; 1.2074x over previous
//
#include <hip/hip_runtime.h>

typedef __attribute__((ext_vector_type(8))) short short8;
typedef __attribute__((ext_vector_type(4))) float f32x4;

static __device__ __forceinline__ unsigned short f2bf(float f) {
  return (unsigned short)((__builtin_bit_cast(unsigned int, f) + 0x8000u) >> 16);
}
static __device__ __forceinline__ float bf2f(unsigned short u) {
  return __builtin_bit_cast(float, ((unsigned)u) << 16);
}
static __device__ __forceinline__ unsigned cvtpk(float a, float b) {
  unsigned r;
  asm("v_cvt_pk_bf16_f32 %0, %1, %2" : "=v"(r) : "v"(a), "v"(b));
  return r;
}

// B=1, Z=H=W=64, C=96, NH=3, HD=32, WS=4, SS=2, N=64 tok/window, NW=4096
constexpr float LOG2E = 1.4426950408889634f;
constexpr float QSCL = 0.17677669529663687f * LOG2E;  // SCL * log2(e), folded into Q
constexpr int XP = 104;   // 208B = 52 dw ≡ 20 (mod 32)
constexpr int KP = 104;
constexpr int VTP = 72;   // 144B

// source index into W[outC][K] for frag-linear element o:
// o = (f*64 + lane)*8 + j ; f = tile*(K/32) + ks
static __device__ __forceinline__ int frag_src(int o, int K) {
  const int j = o & 7;
  const int lane = (o >> 3) & 63;
  const int f = o >> 9;
  const int nks = K >> 5;
  const int ks = f % nks;
  const int t = f / nks;
  const int row = t * 16 + (lane & 15);
  const int k = ks * 32 + (lane >> 4) * 8 + j;
  return row * K + k;
}

// ---- prep: weights -> bf16 frag-linear; (bias+mask)*log2e -> fp32 table ----
// table layout: [v][h][nt][q][kg][r]
__global__ void prep_kernel(const float* __restrict__ qkvw, const float* __restrict__ projw,
                            const float* __restrict__ fc1w, const float* __restrict__ fc2w,
                            const float* __restrict__ relbias,
                            unsigned short* __restrict__ ws, float* __restrict__ tab) {
  int i = blockIdx.x * 256 + threadIdx.x;
  if (i < 27648) ws[i] = f2bf(qkvw[frag_src(i, 96)]);
  if (i < 9216)  ws[27648 + i] = f2bf(projw[frag_src(i, 96)]);
  if (i < 36864) {
    ws[36864 + i] = f2bf(fc1w[frag_src(i, 96)]);
    ws[73728 + i] = f2bf(fc2w[frag_src(i, 384)]);
  }
  if (i < 98304) {
    const int r = i & 3, kgi = (i >> 2) & 3, q = (i >> 4) & 63, nt = (i >> 10) & 3;
    const int vh = i >> 12;           // v*3 + h
    const int h = vh % 3, v = vh / 3;
    const int key = nt * 16 + kgi * 4 + r;
    const bool bz = v & 4, bh = v & 2, bw = v & 1;
    const int iz = q >> 4, ih = (q >> 2) & 3, iw = q & 3;
    const int jz = key >> 4, jh = (key >> 2) & 3, jw = key & 3;
    const int idx = (iz - jz + 3) * 49 + (ih - jh + 3) * 7 + (iw - jw + 3);
    const int ci = (bz ? (iz < 2 ? 9 : 18) : 0) + (bh ? (ih < 2 ? 3 : 6) : 0) +
                   (bw ? (iw < 2 ? 1 : 2) : 0);
    const int cj = (bz ? (jz < 2 ? 9 : 18) : 0) + (bh ? (jh < 2 ? 3 : 6) : 0) +
                   (bw ? (jw < 2 ? 1 : 2) : 0);
    tab[i] = (relbias[idx * 3 + h] + (ci != cj ? -100.f : 0.f)) * LOG2E;
  }
}

// --------- fully fused: LN1+shift+MSA+proj+res + LN2+FC1+GELU+FC2+res -------
__global__ __launch_bounds__(256, 4) void fused_kernel(
    const float* __restrict__ x,
    const float* __restrict__ n1w, const float* __restrict__ n1b,
    const float* __restrict__ qkvb, const float* __restrict__ tab,
    const float* __restrict__ projb,
    const float* __restrict__ n2w, const float* __restrict__ n2b,
    const float* __restrict__ b1, const float* __restrict__ b2,
    const unsigned short* __restrict__ wq, const unsigned short* __restrict__ wp,
    const unsigned short* __restrict__ w1, const unsigned short* __restrict__ w2,
    float* __restrict__ out) {
  __shared__ unsigned short Xo[64 * XP];   // X_ln -> O -> xln2
  __shared__ unsigned short Kb[64 * KP];   // Q -> K overlay -> H1 chunk
  __shared__ unsigned short Vt[96 * VTP];  // [h*32+d][token]; x2 (bf16) after phase 2

  const int tid = threadIdx.x;
  const int bid = blockIdx.x;
  const int wz = bid >> 8, wh = (bid >> 4) & 15, ww = bid & 15;
  const int wave = tid >> 6, lane = tid & 63;
  const int ln = lane & 15, kg = lane >> 4;

  // Phase 0: gather (cyclic shift) + LayerNorm1 -> Xo (wave-local rows)
  {
    const int n = tid >> 2, part = tid & 3;
    const int lz = n >> 4, lh = (n >> 2) & 3, lw = n & 3;
    const int sz = (wz * 4 + lz + 2) & 63;
    const int sh = (wh * 4 + lh + 2) & 63;
    const int sw = (ww * 4 + lw + 2) & 63;
    const float* px = x + (size_t)((sz * 64 + sh) * 64 + sw) * 96 + part * 24;
    float4 v[6];
#pragma unroll
    for (int j = 0; j < 6; ++j) v[j] = ((const float4*)px)[j];
    float s = 0.f, sq = 0.f;
#pragma unroll
    for (int j = 0; j < 6; ++j) {
      s += v[j].x + v[j].y + v[j].z + v[j].w;
      sq += v[j].x * v[j].x + v[j].y * v[j].y + v[j].z * v[j].z + v[j].w * v[j].w;
    }
    s += __shfl_xor(s, 1);  s += __shfl_xor(s, 2);
    sq += __shfl_xor(sq, 1); sq += __shfl_xor(sq, 2);
    const float mean = s * (1.f / 96.f);
    const float var = sq * (1.f / 96.f) - mean * mean;
    const float rs = rsqrtf(var + 1e-5f);
    const float4* g4 = (const float4*)(n1w + part * 24);
    const float4* b4 = (const float4*)(n1b + part * 24);
#pragma unroll
    for (int j = 0; j < 6; ++j) {
      float4 g = g4[j], b = b4[j];
      uint2 o;
      o.x = cvtpk((v[j].x - mean) * rs * g.x + b.x, (v[j].y - mean) * rs * g.y + b.y);
      o.y = cvtpk((v[j].z - mean) * rs * g.z + b.z, (v[j].w - mean) * rs * g.w + b.w);
      *(uint2*)&Xo[n * XP + part * 24 + j * 4] = o;
    }
  }
  // no barrier: phase 1 reads only own-wave Xo rows

  // Phase 1: QKV GEMM, 6-frag register batches. Q pre-scaled by SCL*log2e.
  short8 qa[3];
  {
    short8 a[3];
#pragma unroll
    for (int ks = 0; ks < 3; ++ks)
      a[ks] = *(const short8*)&Xo[(wave * 16 + ln) * XP + ks * 32 + kg * 8];
    // ---- Q (frags 0..17, three 6-batches) ----
#pragma unroll
    for (int g = 0; g < 3; ++g) {
      short8 wf[6];
#pragma unroll
      for (int f = 0; f < 6; ++f)
        wf[f] = *(const short8*)&wq[(size_t)(g * 6 + f) * 512 + lane * 8];
#pragma unroll
      for (int t = 0; t < 2; ++t) {
        const int nt = g * 2 + t;
        const int oc = nt * 16 + ln;
        f32x4 acc = {0.f, 0.f, 0.f, 0.f};
#pragma unroll
        for (int ks = 0; ks < 3; ++ks)
          acc = __builtin_amdgcn_mfma_f32_16x16x32_bf16(a[ks], wf[t * 3 + ks], acc, 0, 0, 0);
        const float bias = qkvb[oc];
#pragma unroll
        for (int r = 0; r < 4; ++r)
          Kb[(wave * 16 + kg * 4 + r) * KP + oc] = f2bf((acc[r] + bias) * QSCL);
      }
    }
    // qa frags (own-wave rows; same-wave in-order LDS allows K overlay after)
#pragma unroll
    for (int h = 0; h < 3; ++h)
      qa[h] = *(const short8*)&Kb[(wave * 16 + ln) * KP + h * 32 + kg * 8];
    // ---- K (frags 18..35), overlays Q region ----
#pragma unroll
    for (int g = 0; g < 3; ++g) {
      short8 wf[6];
#pragma unroll
      for (int f = 0; f < 6; ++f)
        wf[f] = *(const short8*)&wq[(size_t)(18 + g * 6 + f) * 512 + lane * 8];
#pragma unroll
      for (int t = 0; t < 2; ++t) {
        const int nt = g * 2 + t;
        const int oc = 96 + nt * 16 + ln;
        f32x4 acc = {0.f, 0.f, 0.f, 0.f};
#pragma unroll
        for (int ks = 0; ks < 3; ++ks)
          acc = __builtin_amdgcn_mfma_f32_16x16x32_bf16(a[ks], wf[t * 3 + ks], acc, 0, 0, 0);
        const float bias = qkvb[oc];
#pragma unroll
        for (int r = 0; r < 4; ++r)
          Kb[(wave * 16 + kg * 4 + r) * KP + nt * 16 + ln] = f2bf(acc[r] + bias);
      }
    }
    // ---- V (frags 36..53) -> Vt transposed ----
#pragma unroll
    for (int g = 0; g < 3; ++g) {
      short8 wf[6];
#pragma unroll
      for (int f = 0; f < 6; ++f)
        wf[f] = *(const short8*)&wq[(size_t)(36 + g * 6 + f) * 512 + lane * 8];
#pragma unroll
      for (int t = 0; t < 2; ++t) {
        const int nt = g * 2 + t;
        const int oc = 192 + nt * 16 + ln;
        f32x4 acc = {0.f, 0.f, 0.f, 0.f};
#pragma unroll
        for (int ks = 0; ks < 3; ++ks)
          acc = __builtin_amdgcn_mfma_f32_16x16x32_bf16(a[ks], wf[t * 3 + ks], acc, 0, 0, 0);
        const float bias = qkvb[oc];
        uint2 u;
        u.x = cvtpk(acc[0] + bias, acc[1] + bias);
        u.y = cvtpk(acc[2] + bias, acc[3] + bias);
        *(uint2*)&Vt[(nt * 16 + ln) * VTP + wave * 16 + kg * 4] = u;
      }
    }
  }
  __syncthreads();  // K, Vt read cross-wave in phase 2

  // Phase 2: transposed QK^T (S^T = K·Q^T) -> in-register softmax (exp2) -> PV
  const int vv = ((wz == 15) ? 4 : 0) | ((wh == 15) ? 2 : 0) | ((ww == 15) ? 1 : 0);
  const float* tb0 = tab + (size_t)(vv * 3) * 4096;
  const int rowbase = wave * 16 + kg * 4;
  const int lA = ((kg & 1) << 5) + ln;   // source lane kg' = 2*(kg&1)
  const int lB = lA + 16;                // source lane kg' = 2*(kg&1)+1
#pragma unroll
  for (int h = 0; h < 3; ++h) {
    const float* tb = tb0 + h * 4096;
    f32x4 e[4];
#pragma unroll
    for (int nt = 0; nt < 4; ++nt) {
      short8 kf = *(const short8*)&Kb[(nt * 16 + ln) * KP + h * 32 + kg * 8];
      f32x4 trow = *(const f32x4*)(tb + nt * 1024 + (wave * 16 + ln) * 16 + kg * 4);
      f32x4 z = {0.f, 0.f, 0.f, 0.f};
      f32x4 st = __builtin_amdgcn_mfma_f32_16x16x32_bf16(kf, qa[h], z, 0, 0, 0);
#pragma unroll
      for (int r = 0; r < 4; ++r)
        e[nt][r] = __builtin_amdgcn_exp2f(st[r] + trow[r]);  // bounded: no max-sub
    }
    float hs = 0.f;
#pragma unroll
    for (int nt = 0; nt < 4; ++nt)
#pragma unroll
      for (int r = 0; r < 4; ++r) hs += e[nt][r];
    hs += __shfl_xor(hs, 16);
    hs += __shfl_xor(hs, 32);
    const float inv = __builtin_amdgcn_rcpf(hs);
    unsigned pp[4][2];
#pragma unroll
    for (int nt = 0; nt < 4; ++nt) {
      pp[nt][0] = cvtpk(e[nt][0] * inv, e[nt][1] * inv);
      pp[nt][1] = cvtpk(e[nt][2] * inv, e[nt][3] * inv);
    }
    // exchange -> PV A-frags
    short8 paf[2];
#pragma unroll
    for (int ks = 0; ks < 2; ++ks) {
      const unsigned a0 = __shfl((int)pp[2 * ks][0], lA);
      const unsigned a1 = __shfl((int)pp[2 * ks][1], lA);
      const unsigned a2 = __shfl((int)pp[2 * ks][0], lB);
      const unsigned a3 = __shfl((int)pp[2 * ks][1], lB);
      const unsigned b0 = __shfl((int)pp[2 * ks + 1][0], lA);
      const unsigned b1 = __shfl((int)pp[2 * ks + 1][1], lA);
      const unsigned b2 = __shfl((int)pp[2 * ks + 1][0], lB);
      const unsigned b3 = __shfl((int)pp[2 * ks + 1][1], lB);
      const bool hi = (kg >> 1) != 0;
      uint4 wv;
      wv.x = hi ? b0 : a0;
      wv.y = hi ? b1 : a1;
      wv.z = hi ? b2 : a2;
      wv.w = hi ? b3 : a3;
      paf[ks] = __builtin_bit_cast(short8, wv);
    }
#pragma unroll
    for (int dt = 0; dt < 2; ++dt) {
      f32x4 oacc = {0.f, 0.f, 0.f, 0.f};
#pragma unroll
      for (int ks = 0; ks < 2; ++ks) {
        short8 vb = *(const short8*)&Vt[(h * 32 + dt * 16 + ln) * VTP + ks * 32 + kg * 8];
        oacc = __builtin_amdgcn_mfma_f32_16x16x32_bf16(paf[ks], vb, oacc, 0, 0, 0);
      }
#pragma unroll
      for (int r = 0; r < 4; ++r)
        Xo[(rowbase + r) * XP + h * 32 + dt * 16 + ln] = f2bf(oacc[r]);
    }
  }
  __syncthreads();  // all waves done reading Vt before x2 overlays it

  unsigned short* X2b = Vt;  // x2 (bf16) overlay, pitch XP, rows wave-local

  // Phase 3 pass A: proj + shortcut -> x2 (bf16) into X2b; LN2 stats in regs
  int gtok[4];
  float mean_[4], rs_[4];
  {
#pragma unroll
    for (int r = 0; r < 4; ++r) {
      const int n = rowbase + r;
      const int lz = n >> 4, lh = (n >> 2) & 3, lw = n & 3;
      const int oz = (wz * 4 + lz + 2) & 63;
      const int oh = (wh * 4 + lh + 2) & 63;
      const int ow = (ww * 4 + lw + 2) & 63;
      gtok[r] = (oz * 64 + oh) * 64 + ow;
    }
    short8 oa[3];
#pragma unroll
    for (int ks = 0; ks < 3; ++ks)
      oa[ks] = *(const short8*)&Xo[(wave * 16 + ln) * XP + ks * 32 + kg * 8];
    float s_[4] = {0.f, 0.f, 0.f, 0.f}, sq_[4] = {0.f, 0.f, 0.f, 0.f};
#pragma unroll
    for (int g = 0; g < 3; ++g) {
      short8 wf[6];
#pragma unroll
      for (int f = 0; f < 6; ++f)
        wf[f] = *(const short8*)&wp[(size_t)(g * 6 + f) * 512 + lane * 8];
#pragma unroll
      for (int t = 0; t < 2; ++t) {
        const int nt = g * 2 + t;
        const int col = nt * 16 + ln;
        f32x4 acc = {0.f, 0.f, 0.f, 0.f};
#pragma unroll
        for (int ks = 0; ks < 3; ++ks)
          acc = __builtin_amdgcn_mfma_f32_16x16x32_bf16(oa[ks], wf[t * 3 + ks], acc, 0, 0, 0);
        const float pbv = projb[col];
#pragma unroll
        for (int r = 0; r < 4; ++r) {
          const float v = x[(size_t)gtok[r] * 96 + col] + acc[r] + pbv;
          s_[r] += v;
          sq_[r] += v * v;
          X2b[(rowbase + r) * XP + col] = f2bf(v);
        }
      }
    }
#pragma unroll
    for (int r = 0; r < 4; ++r) {
      float s = s_[r], sq = sq_[r];
      s += __shfl_xor(s, 1);  s += __shfl_xor(s, 2);
      s += __shfl_xor(s, 4);  s += __shfl_xor(s, 8);
      sq += __shfl_xor(sq, 1); sq += __shfl_xor(sq, 2);
      sq += __shfl_xor(sq, 4); sq += __shfl_xor(sq, 8);
      const float mean = s * (1.f / 96.f);
      const float var = sq * (1.f / 96.f) - mean * mean;
      mean_[r] = mean;
      rs_[r] = rsqrtf(var + 1e-5f);
    }
  }
  // Phase 3 pass B: read x2 (LDS, own-wave rows) -> LN2 -> xln2 into Xo
#pragma unroll
  for (int nt = 0; nt < 6; ++nt) {
    const int col = nt * 16 + ln;
    const float gw = n2w[col], gb = n2b[col];
#pragma unroll
    for (int r = 0; r < 4; ++r) {
      const float v = bf2f(X2b[(rowbase + r) * XP + col]);
      const float xl = (v - mean_[r]) * rs_[r] * gw + gb;
      Xo[(rowbase + r) * XP + col] = f2bf(xl);
    }
  }

  // xln2 A-frags (own-wave rows)
  short8 a2[3];
#pragma unroll
  for (int ks = 0; ks < 3; ++ks)
    a2[ks] = *(const short8*)&Xo[(wave * 16 + ln) * XP + ks * 32 + kg * 8];

  __syncthreads();  // all waves done reading K (phase 2) before H1 overlays Kb

  // Phase 4: MLP — FC1 (3-frag batches) + poly-GELU -> Kb, FC2 (3-frag groups)
  f32x4 facc[6];
#pragma unroll
  for (int nt = 0; nt < 6; ++nt) facc[nt] = (f32x4){0.f, 0.f, 0.f, 0.f};
#pragma unroll 1
  for (int c = 0; c < 4; ++c) {
#pragma unroll
    for (int nt2 = 0; nt2 < 6; ++nt2) {
      short8 wf1[3];
#pragma unroll
      for (int ks = 0; ks < 3; ++ks)
        wf1[ks] = *(const short8*)&w1[(size_t)(c * 18 + nt2 * 3 + ks) * 512 + lane * 8];
      f32x4 acc = {0.f, 0.f, 0.f, 0.f};
#pragma unroll
      for (int ks = 0; ks < 3; ++ks)
        acc = __builtin_amdgcn_mfma_f32_16x16x32_bf16(a2[ks], wf1[ks], acc, 0, 0, 0);
      const float bb = b1[c * 96 + nt2 * 16 + ln];
#pragma unroll
      for (int r = 0; r < 4; ++r) {
        const float v = acc[r] + bb;
        // gelu via odd-poly CDF approx + clamp (no trans ops)
        const float t2 = v * v;
        float p = fmaf(0.004287f, t2, -0.05694f);
        p = fmaf(p, t2, 0.3952f);
        float phi = fmaf(p, v, 0.5f);
        phi = fminf(fmaxf(phi, 0.f), 1.f);
        Kb[(rowbase + r) * KP + nt2 * 16 + ln] = f2bf(v * phi);
      }
    }
#pragma unroll
    for (int ks2 = 0; ks2 < 3; ++ks2) {
      short8 pa = *(const short8*)&Kb[(wave * 16 + ln) * KP + ks2 * 32 + kg * 8];
#pragma unroll
      for (int g2 = 0; g2 < 2; ++g2) {
        short8 wf2[3];
#pragma unroll
        for (int t = 0; t < 3; ++t)
          wf2[t] = *(const short8*)&w2[(size_t)((g2 * 3 + t) * 12 + c * 3 + ks2) * 512 + lane * 8];
#pragma unroll
        for (int t = 0; t < 3; ++t)
          facc[g2 * 3 + t] =
              __builtin_amdgcn_mfma_f32_16x16x32_bf16(pa, wf2[t], facc[g2 * 3 + t], 0, 0, 0);
      }
    }
  }
  // Epilogue: out = x2 (from LDS) + fc2 + b2, single global write
#pragma unroll
  for (int nt = 0; nt < 6; ++nt) {
    const int col = nt * 16 + ln;
    const float bb = b2[col];
#pragma unroll
    for (int r = 0; r < 4; ++r) {
      const float v = bf2f(X2b[(rowbase + r) * XP + col]);
      out[(size_t)gtok[r] * 96 + col] = v + facc[nt][r] + bb;
    }
  }
}

extern "C" void kernel_launch(void* const* d_in, const int* in_sizes, int n_in,
                              void* d_out, int out_size, void* d_ws, size_t ws_size,
                              hipStream_t stream) {
  const float* x    = (const float*)d_in[0];
  const float* n1w  = (const float*)d_in[1];
  const float* n1b  = (const float*)d_in[2];
  const float* qkvw = (const float*)d_in[3];
  const float* qkvb = (const float*)d_in[4];
  const float* relb = (const float*)d_in[5];
  const float* pw   = (const float*)d_in[6];
  const float* pb   = (const float*)d_in[7];
  const float* n2w  = (const float*)d_in[8];
  const float* n2b  = (const float*)d_in[9];
  const float* w1   = (const float*)d_in[10];
  const float* b1   = (const float*)d_in[11];
  const float* w2   = (const float*)d_in[12];
  const float* b2   = (const float*)d_in[13];
  float* out = (float*)d_out;

  unsigned short* wsq = (unsigned short*)d_ws;   // 27648 bf16 frag-linear
  unsigned short* wsp = wsq + 27648;             // 9216
  unsigned short* ws1 = wsp + 9216;              // 36864
  unsigned short* ws2 = ws1 + 36864;             // 36864
  float* tab = (float*)(wsq + 110592);           // 98304 fp32 bias+mask table

  hipLaunchKernelGGL(prep_kernel, dim3(384), dim3(256), 0, stream,
                     qkvw, pw, w1, w2, relb, wsq, tab);
  hipLaunchKernelGGL(fused_kernel, dim3(4096), dim3(256), 0, stream,
                     x, n1w, n1b, qkvb, tab, pb, n2w, n2b, b1, b2,
                     wsq, wsp, ws1, ws2, out);
}

// Round 13
// 139.034 us; speedup vs baseline: 1.3902x; 1.1514x over previous
//
#include <hip/hip_runtime.h>

typedef __attribute__((ext_vector_type(8))) short short8;
typedef __attribute__((ext_vector_type(4))) float f32x4;

static __device__ __forceinline__ unsigned short f2bf(float f) {
  return (unsigned short)((__builtin_bit_cast(unsigned int, f) + 0x8000u) >> 16);
}
static __device__ __forceinline__ float bf2f(unsigned short u) {
  return __builtin_bit_cast(float, ((unsigned)u) << 16);
}
static __device__ __forceinline__ unsigned cvtpk(float a, float b) {
  unsigned r;
  asm("v_cvt_pk_bf16_f32 %0, %1, %2" : "=v"(r) : "v"(a), "v"(b));
  return r;
}

// B=1, Z=H=W=64, C=96, NH=3, HD=32, WS=4, SS=2, N=64 tok/window, NW=4096
constexpr float LOG2E = 1.4426950408889634f;
constexpr float QSCL = 0.17677669529663687f * LOG2E;  // SCL * log2(e), folded into Q
constexpr int XP = 104;   // 208B = 52 dw ≡ 20 (mod 32)
constexpr int KP = 104;
constexpr int VTP = 72;   // 144B

// source index into W[outC][K] for frag-linear element o:
// o = (f*64 + lane)*8 + j ; f = tile*(K/32) + ks
static __device__ __forceinline__ int frag_src(int o, int K) {
  const int j = o & 7;
  const int lane = (o >> 3) & 63;
  const int f = o >> 9;
  const int nks = K >> 5;
  const int ks = f % nks;
  const int t = f / nks;
  const int row = t * 16 + (lane & 15);
  const int k = ks * 32 + (lane >> 4) * 8 + j;
  return row * K + k;
}

// ---- prep: weights -> bf16 frag-linear; (bias+mask)*log2e -> fp32 table ----
// table layout: [v][h][nt][q][kg][r]
__global__ void prep_kernel(const float* __restrict__ qkvw, const float* __restrict__ projw,
                            const float* __restrict__ fc1w, const float* __restrict__ fc2w,
                            const float* __restrict__ relbias,
                            unsigned short* __restrict__ ws, float* __restrict__ tab) {
  int i = blockIdx.x * 256 + threadIdx.x;
  if (i < 27648) ws[i] = f2bf(qkvw[frag_src(i, 96)]);
  if (i < 9216)  ws[27648 + i] = f2bf(projw[frag_src(i, 96)]);
  if (i < 36864) {
    ws[36864 + i] = f2bf(fc1w[frag_src(i, 96)]);
    ws[73728 + i] = f2bf(fc2w[frag_src(i, 384)]);
  }
  if (i < 98304) {
    const int r = i & 3, kgi = (i >> 2) & 3, q = (i >> 4) & 63, nt = (i >> 10) & 3;
    const int vh = i >> 12;           // v*3 + h
    const int h = vh % 3, v = vh / 3;
    const int key = nt * 16 + kgi * 4 + r;
    const bool bz = v & 4, bh = v & 2, bw = v & 1;
    const int iz = q >> 4, ih = (q >> 2) & 3, iw = q & 3;
    const int jz = key >> 4, jh = (key >> 2) & 3, jw = key & 3;
    const int idx = (iz - jz + 3) * 49 + (ih - jh + 3) * 7 + (iw - jw + 3);
    const int ci = (bz ? (iz < 2 ? 9 : 18) : 0) + (bh ? (ih < 2 ? 3 : 6) : 0) +
                   (bw ? (iw < 2 ? 1 : 2) : 0);
    const int cj = (bz ? (jz < 2 ? 9 : 18) : 0) + (bh ? (jh < 2 ? 3 : 6) : 0) +
                   (bw ? (jw < 2 ? 1 : 2) : 0);
    tab[i] = (relbias[idx * 3 + h] + (ci != cj ? -100.f : 0.f)) * LOG2E;
  }
}

// --------- fully fused, col-split weight loading across waves -------
__global__ __launch_bounds__(256, 3) void fused_kernel(
    const float* __restrict__ x,
    const float* __restrict__ n1w, const float* __restrict__ n1b,
    const float* __restrict__ qkvb, const float* __restrict__ tab,
    const float* __restrict__ projb,
    const float* __restrict__ n2w, const float* __restrict__ n2b,
    const float* __restrict__ b1, const float* __restrict__ b2,
    const unsigned short* __restrict__ wq, const unsigned short* __restrict__ wp,
    const unsigned short* __restrict__ w1, const unsigned short* __restrict__ w2,
    float* __restrict__ out) {
  __shared__ unsigned short Xo[64 * XP];   // X_ln -> O -> xln2
  __shared__ unsigned short Kb[64 * KP];   // Q -> K overlay -> H1 chunk
  __shared__ unsigned short Vt[96 * VTP];  // [h*32+d][token]; x2 (bf16) after phase 2

  const int tid = threadIdx.x;
  const int bid = blockIdx.x;
  const int wz = bid >> 8, wh = (bid >> 4) & 15, ww = bid & 15;
  const int wave = tid >> 6, lane = tid & 63;
  const int ln = lane & 15, kg = lane >> 4;

  // Phase 0: gather (cyclic shift) + LayerNorm1 -> Xo (wave-local rows)
  {
    const int n = tid >> 2, part = tid & 3;
    const int lz = n >> 4, lh = (n >> 2) & 3, lw = n & 3;
    const int sz = (wz * 4 + lz + 2) & 63;
    const int sh = (wh * 4 + lh + 2) & 63;
    const int sw = (ww * 4 + lw + 2) & 63;
    const float* px = x + (size_t)((sz * 64 + sh) * 64 + sw) * 96 + part * 24;
    float4 v[6];
#pragma unroll
    for (int j = 0; j < 6; ++j) v[j] = ((const float4*)px)[j];
    float s = 0.f, sq = 0.f;
#pragma unroll
    for (int j = 0; j < 6; ++j) {
      s += v[j].x + v[j].y + v[j].z + v[j].w;
      sq += v[j].x * v[j].x + v[j].y * v[j].y + v[j].z * v[j].z + v[j].w * v[j].w;
    }
    s += __shfl_xor(s, 1);  s += __shfl_xor(s, 2);
    sq += __shfl_xor(sq, 1); sq += __shfl_xor(sq, 2);
    const float mean = s * (1.f / 96.f);
    const float var = sq * (1.f / 96.f) - mean * mean;
    const float rs = rsqrtf(var + 1e-5f);
    const float4* g4 = (const float4*)(n1w + part * 24);
    const float4* b4 = (const float4*)(n1b + part * 24);
#pragma unroll
    for (int j = 0; j < 6; ++j) {
      float4 g = g4[j], b = b4[j];
      uint2 o;
      o.x = cvtpk((v[j].x - mean) * rs * g.x + b.x, (v[j].y - mean) * rs * g.y + b.y);
      o.y = cvtpk((v[j].z - mean) * rs * g.z + b.z, (v[j].w - mean) * rs * g.w + b.w);
      *(uint2*)&Xo[n * XP + part * 24 + j * 4] = o;
    }
  }
  // no barrier yet: Q reads only own-wave Xo rows

  // Phase 1a: Q GEMM (row-split, own rows), Q pre-scaled by SCL*log2e
  short8 qa[3];
  {
    short8 a[3];
#pragma unroll
    for (int ks = 0; ks < 3; ++ks)
      a[ks] = *(const short8*)&Xo[(wave * 16 + ln) * XP + ks * 32 + kg * 8];
#pragma unroll
    for (int g = 0; g < 3; ++g) {
      short8 wf[6];
#pragma unroll
      for (int f = 0; f < 6; ++f)
        wf[f] = *(const short8*)&wq[(size_t)(g * 6 + f) * 512 + lane * 8];
#pragma unroll
      for (int t = 0; t < 2; ++t) {
        const int nt = g * 2 + t;
        const int oc = nt * 16 + ln;
        f32x4 acc = {0.f, 0.f, 0.f, 0.f};
#pragma unroll
        for (int ks = 0; ks < 3; ++ks)
          acc = __builtin_amdgcn_mfma_f32_16x16x32_bf16(a[ks], wf[t * 3 + ks], acc, 0, 0, 0);
        const float bias = qkvb[oc];
#pragma unroll
        for (int r = 0; r < 4; ++r)
          Kb[(wave * 16 + kg * 4 + r) * KP + oc] = f2bf((acc[r] + bias) * QSCL);
      }
    }
    // qa frags (own rows; same-wave in-order LDS)
#pragma unroll
    for (int h = 0; h < 3; ++h)
      qa[h] = *(const short8*)&Kb[(wave * 16 + ln) * KP + h * 32 + kg * 8];
  }
  __syncthreads();  // A: Xo visible cross-wave; all qa reads done before K overlay

  // Phase 1b: K,V col-split — wave owns 3 tiles of {K:6..11, V:12..17}, all rows
  {
    const int t0 = wave < 2 ? 6 + 2 * wave : 8 + wave;       // 6,8 | 10,11
    const int t1 = wave < 2 ? 7 + 2 * wave : 10 + 2 * wave;  // 7,9 | 14,16
    const int t2 = wave < 2 ? 12 + wave : 11 + 2 * wave;     // 12,13 | 15,17
#pragma unroll
    for (int i = 0; i < 3; ++i) {
      const int tile = i == 0 ? t0 : (i == 1 ? t1 : t2);
      const int oc = tile * 16 + ln;
      short8 wf[3];
#pragma unroll
      for (int ks = 0; ks < 3; ++ks)
        wf[ks] = *(const short8*)&wq[(size_t)(tile * 3 + ks) * 512 + lane * 8];
      const float bias = qkvb[oc];
#pragma unroll
      for (int rt = 0; rt < 4; ++rt) {
        f32x4 acc = {0.f, 0.f, 0.f, 0.f};
#pragma unroll
        for (int ks = 0; ks < 3; ++ks) {
          short8 a = *(const short8*)&Xo[(rt * 16 + ln) * XP + ks * 32 + kg * 8];
          acc = __builtin_amdgcn_mfma_f32_16x16x32_bf16(a, wf[ks], acc, 0, 0, 0);
        }
        if (tile < 12) {  // K
#pragma unroll
          for (int r = 0; r < 4; ++r)
            Kb[(rt * 16 + kg * 4 + r) * KP + (tile - 12 + 6) * 16 + ln] = f2bf(acc[r] + bias);
        } else {          // V (transposed)
          uint2 u;
          u.x = cvtpk(acc[0] + bias, acc[1] + bias);
          u.y = cvtpk(acc[2] + bias, acc[3] + bias);
          *(uint2*)&Vt[((tile - 12) * 16 + ln) * VTP + rt * 16 + kg * 4] = u;
        }
      }
    }
  }
  __syncthreads();  // B: K, Vt ready for cross-wave phase 2

  // Phase 2: transposed QK^T -> in-register softmax (exp2) -> PV (row-split)
  const int vv = ((wz == 15) ? 4 : 0) | ((wh == 15) ? 2 : 0) | ((ww == 15) ? 1 : 0);
  const float* tb0 = tab + (size_t)(vv * 3) * 4096;
  const int rowbase = wave * 16 + kg * 4;
  const int lA = ((kg & 1) << 5) + ln;
  const int lB = lA + 16;
#pragma unroll
  for (int h = 0; h < 3; ++h) {
    const float* tb = tb0 + h * 4096;
    f32x4 e[4];
#pragma unroll
    for (int nt = 0; nt < 4; ++nt) {
      short8 kf = *(const short8*)&Kb[(nt * 16 + ln) * KP + h * 32 + kg * 8];
      f32x4 trow = *(const f32x4*)(tb + nt * 1024 + (wave * 16 + ln) * 16 + kg * 4);
      f32x4 z = {0.f, 0.f, 0.f, 0.f};
      f32x4 st = __builtin_amdgcn_mfma_f32_16x16x32_bf16(kf, qa[h], z, 0, 0, 0);
#pragma unroll
      for (int r = 0; r < 4; ++r)
        e[nt][r] = __builtin_amdgcn_exp2f(st[r] + trow[r]);  // bounded: no max-sub
    }
    float hs = 0.f;
#pragma unroll
    for (int nt = 0; nt < 4; ++nt)
#pragma unroll
      for (int r = 0; r < 4; ++r) hs += e[nt][r];
    hs += __shfl_xor(hs, 16);
    hs += __shfl_xor(hs, 32);
    const float inv = __builtin_amdgcn_rcpf(hs);
    unsigned pp[4][2];
#pragma unroll
    for (int nt = 0; nt < 4; ++nt) {
      pp[nt][0] = cvtpk(e[nt][0] * inv, e[nt][1] * inv);
      pp[nt][1] = cvtpk(e[nt][2] * inv, e[nt][3] * inv);
    }
    short8 paf[2];
#pragma unroll
    for (int ks = 0; ks < 2; ++ks) {
      const unsigned a0 = __shfl((int)pp[2 * ks][0], lA);
      const unsigned a1 = __shfl((int)pp[2 * ks][1], lA);
      const unsigned a2 = __shfl((int)pp[2 * ks][0], lB);
      const unsigned a3 = __shfl((int)pp[2 * ks][1], lB);
      const unsigned b0 = __shfl((int)pp[2 * ks + 1][0], lA);
      const unsigned b1 = __shfl((int)pp[2 * ks + 1][1], lA);
      const unsigned b2 = __shfl((int)pp[2 * ks + 1][0], lB);
      const unsigned b3 = __shfl((int)pp[2 * ks + 1][1], lB);
      const bool hi = (kg >> 1) != 0;
      uint4 wv;
      wv.x = hi ? b0 : a0;
      wv.y = hi ? b1 : a1;
      wv.z = hi ? b2 : a2;
      wv.w = hi ? b3 : a3;
      paf[ks] = __builtin_bit_cast(short8, wv);
    }
#pragma unroll
    for (int dt = 0; dt < 2; ++dt) {
      f32x4 oacc = {0.f, 0.f, 0.f, 0.f};
#pragma unroll
      for (int ks = 0; ks < 2; ++ks) {
        short8 vb = *(const short8*)&Vt[(h * 32 + dt * 16 + ln) * VTP + ks * 32 + kg * 8];
        oacc = __builtin_amdgcn_mfma_f32_16x16x32_bf16(paf[ks], vb, oacc, 0, 0, 0);
      }
#pragma unroll
      for (int r = 0; r < 4; ++r)
        Xo[(rowbase + r) * XP + h * 32 + dt * 16 + ln] = f2bf(oacc[r]);
    }
  }
  __syncthreads();  // C: all waves done reading Vt before x2 overlays it

  unsigned short* X2b = Vt;  // x2 (bf16) overlay, pitch XP

  // Phase 3: proj (row-split) -> x2 into X2b + LN2 stats; pass B xln2 -> Xo
  {
    int gtok[4];
#pragma unroll
    for (int r = 0; r < 4; ++r) {
      const int n = rowbase + r;
      const int lz = n >> 4, lh = (n >> 2) & 3, lw = n & 3;
      const int oz = (wz * 4 + lz + 2) & 63;
      const int oh = (wh * 4 + lh + 2) & 63;
      const int ow = (ww * 4 + lw + 2) & 63;
      gtok[r] = (oz * 64 + oh) * 64 + ow;
    }
    short8 oa[3];
#pragma unroll
    for (int ks = 0; ks < 3; ++ks)
      oa[ks] = *(const short8*)&Xo[(wave * 16 + ln) * XP + ks * 32 + kg * 8];
    float s_[4] = {0.f, 0.f, 0.f, 0.f}, sq_[4] = {0.f, 0.f, 0.f, 0.f};
#pragma unroll
    for (int g = 0; g < 3; ++g) {
      short8 wf[6];
#pragma unroll
      for (int f = 0; f < 6; ++f)
        wf[f] = *(const short8*)&wp[(size_t)(g * 6 + f) * 512 + lane * 8];
#pragma unroll
      for (int t = 0; t < 2; ++t) {
        const int nt = g * 2 + t;
        const int col = nt * 16 + ln;
        f32x4 acc = {0.f, 0.f, 0.f, 0.f};
#pragma unroll
        for (int ks = 0; ks < 3; ++ks)
          acc = __builtin_amdgcn_mfma_f32_16x16x32_bf16(oa[ks], wf[t * 3 + ks], acc, 0, 0, 0);
        const float pbv = projb[col];
#pragma unroll
        for (int r = 0; r < 4; ++r) {
          const float v = x[(size_t)gtok[r] * 96 + col] + acc[r] + pbv;
          s_[r] += v;
          sq_[r] += v * v;
          X2b[(rowbase + r) * XP + col] = f2bf(v);
        }
      }
    }
#pragma unroll
    for (int r = 0; r < 4; ++r) {
      float s = s_[r], sq = sq_[r];
      s += __shfl_xor(s, 1);  s += __shfl_xor(s, 2);
      s += __shfl_xor(s, 4);  s += __shfl_xor(s, 8);
      sq += __shfl_xor(sq, 1); sq += __shfl_xor(sq, 2);
      sq += __shfl_xor(sq, 4); sq += __shfl_xor(sq, 8);
      const float mean = s * (1.f / 96.f);
      const float var = sq * (1.f / 96.f) - mean * mean;
      const float rs = rsqrtf(var + 1e-5f);
      s_[r] = mean;   // reuse
      sq_[r] = rs;
    }
    // pass B: xln2 into Xo (own rows)
#pragma unroll
    for (int nt = 0; nt < 6; ++nt) {
      const int col = nt * 16 + ln;
      const float gw = n2w[col], gb = n2b[col];
#pragma unroll
      for (int r = 0; r < 4; ++r) {
        const float v = bf2f(X2b[(rowbase + r) * XP + col]);
        const float xl = (v - s_[r]) * sq_[r] * gw + gb;
        Xo[(rowbase + r) * XP + col] = f2bf(xl);
      }
    }
  }

  // Phase 4: MLP col-split. FC1 tiles/chunk: w0:{0} w1:{1} w2:{2,3} w3:{4,5};
  // FC2 output tiles (fixed): w0:{0,1} w1:{2,3} w2:{4} w3:{5}. Balanced 36 MFMA/chunk.
  const int nf1 = (wave < 2) ? 1 : 2;
  const int f1base = (wave < 2) ? wave : 2 + 2 * (wave - 2);
  const int nf2 = (wave < 2) ? 2 : 1;
  const int f2base = (wave < 2) ? 2 * wave : 2 + wave;
  f32x4 acc2[2][4];
#pragma unroll
  for (int i = 0; i < 2; ++i)
#pragma unroll
    for (int rt = 0; rt < 4; ++rt) acc2[i][rt] = (f32x4){0.f, 0.f, 0.f, 0.f};

#pragma unroll 1
  for (int c = 0; c < 4; ++c) {
    __syncthreads();  // xln2 visible (c=0) / H1 of prev chunk consumed; K region dead
    // FC1 (col-split, all rows) + poly-GELU -> Kb
#pragma unroll
    for (int i = 0; i < 2; ++i) {
      if (i < nf1) {
        const int tile = f1base + i;
        short8 wf1[3];
#pragma unroll
        for (int ks = 0; ks < 3; ++ks)
          wf1[ks] = *(const short8*)&w1[(size_t)(c * 18 + tile * 3 + ks) * 512 + lane * 8];
        const float bb = b1[c * 96 + tile * 16 + ln];
#pragma unroll
        for (int rt = 0; rt < 4; ++rt) {
          f32x4 acc = {0.f, 0.f, 0.f, 0.f};
#pragma unroll
          for (int ks = 0; ks < 3; ++ks) {
            short8 a = *(const short8*)&Xo[(rt * 16 + ln) * XP + ks * 32 + kg * 8];
            acc = __builtin_amdgcn_mfma_f32_16x16x32_bf16(a, wf1[ks], acc, 0, 0, 0);
          }
#pragma unroll
          for (int r = 0; r < 4; ++r) {
            const float v = acc[r] + bb;
            const float t2 = v * v;
            float p = fmaf(0.004287f, t2, -0.05694f);
            p = fmaf(p, t2, 0.3952f);
            float phi = fmaf(p, v, 0.5f);
            phi = fminf(fmaxf(phi, 0.f), 1.f);
            Kb[(rt * 16 + kg * 4 + r) * KP + tile * 16 + ln] = f2bf(v * phi);
          }
        }
      }
    }
    __syncthreads();  // H1 ready
    // FC2 (col-split, all rows), accumulate across chunks
#pragma unroll
    for (int ks = 0; ks < 3; ++ks) {
      short8 wf2[2];
#pragma unroll
      for (int i = 0; i < 2; ++i)
        if (i < nf2)
          wf2[i] = *(const short8*)&w2[(size_t)((f2base + i) * 12 + c * 3 + ks) * 512 + lane * 8];
#pragma unroll
      for (int rt = 0; rt < 4; ++rt) {
        short8 pa = *(const short8*)&Kb[(rt * 16 + ln) * KP + ks * 32 + kg * 8];
#pragma unroll
        for (int i = 0; i < 2; ++i)
          if (i < nf2)
            acc2[i][rt] = __builtin_amdgcn_mfma_f32_16x16x32_bf16(pa, wf2[i], acc2[i][rt], 0, 0, 0);
      }
    }
  }

  // Epilogue (col-split): out = x2 (LDS) + fc2 + b2, single global write
#pragma unroll
  for (int i = 0; i < 2; ++i) {
    if (i < nf2) {
      const int col = (f2base + i) * 16 + ln;
      const float bb = b2[col];
#pragma unroll
      for (int rt = 0; rt < 4; ++rt) {
#pragma unroll
        for (int r = 0; r < 4; ++r) {
          const int n = rt * 16 + kg * 4 + r;
          const int lz = n >> 4, lh = (n >> 2) & 3, lw = n & 3;
          const int oz = (wz * 4 + lz + 2) & 63;
          const int oh = (wh * 4 + lh + 2) & 63;
          const int ow = (ww * 4 + lw + 2) & 63;
          const size_t gt = (size_t)((oz * 64 + oh) * 64 + ow);
          const float v = bf2f(X2b[n * XP + col]);
          out[gt * 96 + col] = v + acc2[i][rt][r] + bb;
        }
      }
    }
  }
}

extern "C" void kernel_launch(void* const* d_in, const int* in_sizes, int n_in,
                              void* d_out, int out_size, void* d_ws, size_t ws_size,
                              hipStream_t stream) {
  const float* x    = (const float*)d_in[0];
  const float* n1w  = (const float*)d_in[1];
  const float* n1b  = (const float*)d_in[2];
  const float* qkvw = (const float*)d_in[3];
  const float* qkvb = (const float*)d_in[4];
  const float* relb = (const float*)d_in[5];
  const float* pw   = (const float*)d_in[6];
  const float* pb   = (const float*)d_in[7];
  const float* n2w  = (const float*)d_in[8];
  const float* n2b  = (const float*)d_in[9];
  const float* w1   = (const float*)d_in[10];
  const float* b1   = (const float*)d_in[11];
  const float* w2   = (const float*)d_in[12];
  const float* b2   = (const float*)d_in[13];
  float* out = (float*)d_out;

  unsigned short* wsq = (unsigned short*)d_ws;   // 27648 bf16 frag-linear
  unsigned short* wsp = wsq + 27648;             // 9216
  unsigned short* ws1 = wsp + 9216;              // 36864
  unsigned short* ws2 = ws1 + 36864;             // 36864
  float* tab = (float*)(wsq + 110592);           // 98304 fp32 bias+mask table

  hipLaunchKernelGGL(prep_kernel, dim3(384), dim3(256), 0, stream,
                     qkvw, pw, w1, w2, relb, wsq, tab);
  hipLaunchKernelGGL(fused_kernel, dim3(4096), dim3(256), 0, stream,
                     x, n1w, n1b, qkvb, tab, pb, n2w, n2b, b1, b2,
                     wsq, wsp, ws1, ws2, out);
}